// Round 10
// baseline (82.291 us; speedup 1.0000x reference)
//
#include <hip/hip_runtime.h>
#include <hip/hip_bf16.h>

#define EPS 1e-6f

typedef __attribute__((ext_vector_type(8))) __bf16 bf16x8;
typedef __attribute__((ext_vector_type(4))) float f32x4;

__device__ inline unsigned short f2bf_rtne(float f) {
    unsigned int u = __float_as_uint(f);
    unsigned int r = (u + 0x7FFFu + ((u >> 16) & 1u)) >> 16;
    return (unsigned short)r;
}

// prep: p -> bf16 (row-major) + row sum of squares (f32, unrounded input).
// One wave per row. ~4MB read / 2MB write => ~3 us.
__global__ void p_prep(const float* __restrict__ in,
                       unsigned short* __restrict__ hi,
                       float* __restrict__ sq, int R, int D) {
    int wid = (blockIdx.x * blockDim.x + threadIdx.x) >> 6;
    int lane = threadIdx.x & 63;
    if (wid >= R) return;
    const float4* rp = (const float4*)(in + (size_t)wid * D);
    ushort4* hp = (ushort4*)(hi + (size_t)wid * D);
    float s = 0.f;
    int nvec = D >> 2;
    for (int j = lane; j < nvec; j += 64) {
        float4 v = rp[j];
        float fv[4] = {v.x, v.y, v.z, v.w};
        ushort4 h4;
        unsigned short* hh = (unsigned short*)&h4;
#pragma unroll
        for (int i = 0; i < 4; ++i) {
            float f = fv[i];
            s += f * f;
            hh[i] = f2bf_rtne(f);
        }
        hp[j] = h4;
    }
#pragma unroll
    for (int off = 32; off; off >>= 1) s += __shfl_down(s, off);
    if (lane == 0) sq[wid] = s;
}

// ---------------------------------------------------------------------------
// Fused yat kernel, B-side via global_load_lds (pre-converted phi).
// 256x256 tile, 512 threads, r5's 4-phase schedule. A (x) reg-staged with
// in-flight bf16 cvt + sumsq (2x 16-reg ping-pong chunks, issue ph3 ->
// write ph1/ph2 next tile). B staged direct-to-LDS (4 gload_lds dwordx4 per
// thread per tile, pre-swizzled global source col, 2-tile pipeline depth;
// residency self-synchronized by the compiler's vmcnt wait on the younger
// A-chunk loads at ph1).
// out = dots^2 / (xsq + psq - 2*dots + eps)
// ---------------------------------------------------------------------------
__global__ __launch_bounds__(512, 2) void yat_fused(
    const float* __restrict__ X, const unsigned short* __restrict__ Phi,
    const float* __restrict__ psq, float* __restrict__ out,
    int M, int N, int K) {

    __shared__ __align__(128) char sm[131072];   // 2 slots x (A 32KB + B 32KB)
    __shared__ __align__(16) float sqx[256];
    const char* smc = (const char*)sm;

    const int t = threadIdx.x;
    const int lane = t & 63;
    const int wid = t >> 6;        // 0..7
    const int wm = wid >> 2;       // 0..1  (row half of block)
    const int wn = wid & 3;        // 0..3  (col quarter of block)

    // T1: bijective XCD swizzle (total % 8 == 0 guaranteed by launch guard)
    const int nbx = N >> 8;
    const int nby = M >> 8;
    const int total = nbx * nby;
    int bid = blockIdx.x;
    bid = (bid & 7) * (total >> 3) + (bid >> 3);
    const int by = bid / nbx;
    const int bx = bid - by * nbx;
    const int brow = by << 8;
    const int bcol = bx << 8;

    const int NKT = K >> 6;         // K-tiles (16)

    f32x4 acc[8][4];
#pragma unroll
    for (int i = 0; i < 8; ++i)
#pragma unroll
        for (int j = 0; j < 4; ++j) acc[i][j] = (f32x4){0.f, 0.f, 0.f, 0.f};

    const int arow = lane & 15;           // fragment row/col within 16
    const int kq16 = (lane >> 4) * 16;    // byte offset of k-slot within 32-k half

    // ---- staging geometry ----
    const int rsub = lane >> 3;
    const int lcq = (lane & 7) ^ rsub;    // pre-swizzled logical col16
    const long baseA = (long)(brow + wid * 8 + rsub) * K + lcq * 8;
    const long sH = (long)128 * K, sL = (long)64 * K;   // uniform (SGPR)
    const int dlane = wid * 1024 + lane * 16;
    const size_t rowB = (size_t)K * 2;                  // phi row bytes
    const int stgc = ((lane & 7) ^ rsub) << 4;          // pre-swizzled src col (bytes)

    f32x4 c0[4], c1[4];                           // A chunk ping-pong (16 regs each)
    float qA[2][2] = {{0.f, 0.f}, {0.f, 0.f}};    // x sum-of-squares accums

    // issue A chunks for tile kt: c0 = rows hh=0 (l=0,1), c1 = hh=1
#define ISSUE_A(kt) do {                                                       \
    const float* g_ = X + baseA + (long)(kt) * 64;                             \
    c0[0] = *(const f32x4*)(g_);            c0[1] = *(const f32x4*)(g_ + 4);   \
    c0[2] = *(const f32x4*)(g_ + sL);       c0[3] = *(const f32x4*)(g_ + sL + 4);\
    c1[0] = *(const f32x4*)(g_ + sH);       c1[1] = *(const f32x4*)(g_ + sH + 4);\
    c1[2] = *(const f32x4*)(g_ + sH + sL);  c1[3] = *(const f32x4*)(g_ + sH + sL + 4);\
} while (0)

    // cvt + sumsq + ds_write one A chunk (hh half) into slot
#define WRITE_C(buf, hh, slot) do {                                            \
    _Pragma("unroll")                                                          \
    for (int l_ = 0; l_ < 2; ++l_) {                                           \
        f32x4 u_ = buf[2 * l_], v_ = buf[2 * l_ + 1];                          \
        qA[hh][l_] += u_[0]*u_[0] + u_[1]*u_[1] + u_[2]*u_[2] + u_[3]*u_[3]    \
                    + v_[0]*v_[0] + v_[1]*v_[1] + v_[2]*v_[2] + v_[3]*v_[3];   \
        bf16x8 pk_;                                                            \
        _Pragma("unroll")                                                      \
        for (int i_ = 0; i_ < 4; ++i_) {                                       \
            pk_[i_]     = (__bf16)u_[i_];                                      \
            pk_[4 + i_] = (__bf16)v_[i_];                                      \
        }                                                                      \
        *(bf16x8*)((char*)sm + (slot) * 65536 + (hh) * 16384 + l_ * 8192       \
                   + dlane) = pk_;                                             \
    }                                                                          \
} while (0)

    // B tile kt -> LDS slot (kt&1) via global_load_lds (wave-linear dest,
    // pre-swizzled source col: verified pattern from rounds 0-3)
#define STAGE_B(kt) do {                                                       \
    const size_t k0b_ = (size_t)(kt) << 7;   /* 64 elems * 2B */               \
    char* lb_ = (char*)sm + ((kt) & 1) * 65536 + 32768;                        \
    _Pragma("unroll")                                                          \
    for (int l_ = 0; l_ < 4; ++l_) {                                           \
        int rl_ = (l_ * 8 + wid) * 8 + rsub;                                   \
        const char* src_ = (const char*)Phi + (size_t)(bcol + rl_) * rowB      \
                           + k0b_ + stgc;                                      \
        __builtin_amdgcn_global_load_lds(                                      \
            (const __attribute__((address_space(1))) void*)src_,               \
            (__attribute__((address_space(3))) void*)(lb_ + (l_ * 8 + wid) * 1024),\
            16, 0, 0);                                                         \
    }                                                                          \
} while (0)

#define READ_A(slot, mh) do {                                                  \
    _Pragma("unroll")                                                          \
    for (int mi_ = 0; mi_ < 4; ++mi_) {                                        \
        int r_ = wm * 128 + (mh) * 64 + mi_ * 16 + arow;                       \
        const char* p_ = smc + (slot) * 65536 + r_ * 128;                      \
        int s_ = (r_ & 7) << 4;                                                \
        af[mi_][0] = *(const bf16x8*)(p_ + (kq16 ^ s_));                       \
        af[mi_][1] = *(const bf16x8*)(p_ + ((64 + kq16) ^ s_));                \
    }                                                                          \
} while (0)

#define READ_B(slot, nh, dst) do {                                             \
    _Pragma("unroll")                                                          \
    for (int ni_ = 0; ni_ < 2; ++ni_) {                                        \
        int r_ = wn * 64 + (nh) * 32 + ni_ * 16 + arow;                        \
        const char* p_ = smc + (slot) * 65536 + 32768 + r_ * 128;              \
        int s_ = (r_ & 7) << 4;                                                \
        dst[ni_][0] = *(const bf16x8*)(p_ + (kq16 ^ s_));                      \
        dst[ni_][1] = *(const bf16x8*)(p_ + ((64 + kq16) ^ s_));               \
    }                                                                          \
} while (0)

#define MFMA_Q(mh, nh, bset) do {                                              \
    __builtin_amdgcn_s_setprio(1);                                             \
    _Pragma("unroll")                                                          \
    for (int kk_ = 0; kk_ < 2; ++kk_)                                          \
        _Pragma("unroll")                                                      \
        for (int mi_ = 0; mi_ < 4; ++mi_)                                      \
            _Pragma("unroll")                                                  \
            for (int ni_ = 0; ni_ < 2; ++ni_)                                  \
                acc[(mh) * 4 + mi_][(nh) * 2 + ni_] =                          \
                    __builtin_amdgcn_mfma_f32_16x16x32_bf16(                   \
                        af[mi_][kk_], bset[ni_][kk_],                          \
                        acc[(mh) * 4 + mi_][(nh) * 2 + ni_], 0, 0, 0);         \
    __builtin_amdgcn_s_setprio(0);                                             \
} while (0)

#define PBAR() do {                                                            \
    __builtin_amdgcn_s_barrier();                                              \
    __builtin_amdgcn_sched_barrier(0);                                         \
    asm volatile("" ::: "memory");                                             \
} while (0)
#define LGKMDRAIN() asm volatile("s_waitcnt lgkmcnt(0)" ::: "memory")
#define VMCNT(n) asm volatile("s_waitcnt vmcnt(" #n ")" ::: "memory")

    bf16x8 af[4][2];              // A-half frags (overwritten ph3)
    bf16x8 bf0[2][2], bf1[2][2];  // B-quarter frags, live across the tile

    // prologue: A(0) staged via chunks (waits drain inline); B(0)->slot0,
    // B(1)->slot1; prime chunks with A(1); drain B; barrier.
    ISSUE_A(0);
    WRITE_C(c0, 0, 0);
    WRITE_C(c1, 1, 0);
    STAGE_B(0);
    STAGE_B(1);
    ISSUE_A(1);
    VMCNT(8);          // drain B(0)+B(1); leave A(1)'s 8 loads in flight
    LGKMDRAIN();
    PBAR();

    for (int kt = 0; kt < NKT; ++kt) {
        const int slot = kt & 1;
        const int nslot = slot ^ 1;
        const bool more = (kt + 1) < NKT;
        const bool more2 = (kt + 2) < NKT;

        // ph1: write A(kt+1).hh0 -> nslot; Q00
        if (more) WRITE_C(c0, 0, nslot);
        READ_A(slot, 0); READ_B(slot, 0, bf0);
        MFMA_Q(0, 0, bf0); PBAR();
        // ph2: write A(kt+1).hh1 -> nslot; Q01
        if (more) WRITE_C(c1, 1, nslot);
        READ_B(slot, 1, bf1);
        MFMA_Q(0, 1, bf1); PBAR();
        // ph3: stage B(kt+2) -> slot (B reads of this slot done at ph2 bar);
        //      issue A(kt+2) chunks; Q10
        if (more2) { STAGE_B(kt + 2); ISSUE_A(kt + 2); }
        READ_A(slot, 1);
        MFMA_Q(1, 0, bf0); PBAR();
        // ph4: Q11; drain A ds_writes; publish barrier
        MFMA_Q(1, 1, bf1);
        LGKMDRAIN();
        PBAR();
    }

#undef ISSUE_A
#undef WRITE_C
#undef STAGE_B
#undef READ_A
#undef READ_B
#undef MFMA_Q
#undef PBAR
#undef LGKMDRAIN
#undef VMCNT

    // ---- reduce per-thread x sum-of-squares into sqx ----
    // Row (hh*128 + l*64 + wid*8 + rsub) covered by the 8 lanes sharing rsub.
#pragma unroll
    for (int hh = 0; hh < 2; ++hh)
#pragma unroll
        for (int l = 0; l < 2; ++l) {
            float a = qA[hh][l];
#pragma unroll
            for (int m = 1; m <= 4; m <<= 1) a += __shfl_xor(a, m);
            if ((lane & 7) == 0) sqx[hh * 128 + l * 64 + wid * 8 + rsub] = a;
        }

    // epilogue: score = d^2 / (xsq + psq - 2d + eps), staged through LDS for
    // full-line f32x4 stores. Two passes of 128 rows (wm half each).
    // Swizzle: logical (row,col) at physical col ^ (((row>>2)&1)<<4).
    float* smf = (float*)sm;
#pragma unroll
    for (int pass = 0; pass < 2; ++pass) {
        __syncthreads();
        if (wm == pass) {
#pragma unroll
            for (int ni = 0; ni < 4; ++ni) {
                int lcc = wn * 64 + ni * 16 + arow;
                float ps = psq[bcol + lcc];
#pragma unroll
                for (int mi = 0; mi < 8; ++mi) {
                    f32x4 c = acc[mi][ni];
                    int lr0 = mi * 16 + (lane >> 4) * 4;   // local row, mult of 4
                    f32x4 xs4 = *(const f32x4*)(&sqx[pass * 128 + lr0]);
                    int lcs = lcc ^ (((lr0 >> 2) & 1) << 4);
#pragma unroll
                    for (int j = 0; j < 4; ++j) {
                        float dv = c[j];
                        float denom = xs4[j] + ps - 2.0f * dv + EPS;
                        smf[(lr0 + j) * 256 + lcs] = dv * dv / denom;
                    }
                }
            }
        }
        __syncthreads();
#pragma unroll
        for (int rr = 0; rr < 16; ++rr) {
            int r = wid * 16 + rr;
            int swz = ((r >> 2) & 1) << 4;
            int c0l = lane * 4;                             // logical col
            f32x4 v = *(const f32x4*)(smf + r * 256 + (c0l ^ swz));
            *(f32x4*)(out + (size_t)(brow + pass * 128 + r) * N + bcol + c0l) = v;
        }
    }
}

__global__ void yat_fallback(const float* __restrict__ x, const float* __restrict__ p,
                             float* __restrict__ out, int B, int P, int D) {
    __shared__ float xs[1024];
    int b = blockIdx.x;
    int pc = blockIdx.y * 256 + threadIdx.x;
    for (int i = threadIdx.x; i < D; i += 256) xs[i] = x[(size_t)b * D + i];
    __syncthreads();
    if (pc >= P) return;
    float dot = 0.f, psq = 0.f, xsq = 0.f;
    for (int k = 0; k < D; ++k) {
        float pv = p[(size_t)pc * D + k];
        float xv = xs[k];
        dot += xv * pv;
        psq += pv * pv;
        xsq += xv * xv;
    }
    float denom = xsq + psq - 2.f * dot + EPS;
    out[(size_t)b * P + pc] = dot * dot / denom;
}

extern "C" void kernel_launch(void* const* d_in, const int* in_sizes, int n_in,
                              void* d_out, int out_size, void* d_ws, size_t ws_size,
                              hipStream_t stream) {
    const float* x = (const float*)d_in[0];
    const float* p = (const float*)d_in[1];
    float* out = (float*)d_out;

    const int D = 1024;
    const int B = in_sizes[0] / D;
    const int P = in_sizes[1] / D;

    size_t need = (size_t)P * D * 2 + (size_t)P * 4;
    int nblocks = (B / 256) * (P / 256);
    if (ws_size < need || (B % 256) || (P % 256) || (D % 64) || (nblocks % 8)) {
        yat_fallback<<<dim3(B, (P + 255) / 256), 256, 0, stream>>>(x, p, out, B, P, D);
        return;
    }

    unsigned short* phi = (unsigned short*)d_ws;
    float* psq = (float*)(phi + (size_t)P * D);

    p_prep<<<(P + 3) / 4, 256, 0, stream>>>(p, phi, psq, P, D);
    yat_fused<<<dim3(nblocks), 512, 0, stream>>>(x, phi, psq, out, B, P, D);
}

// Round 11
// 58.805 us; speedup vs baseline: 1.3994x; 1.3994x over previous
//
#include <hip/hip_runtime.h>
#include <hip/hip_bf16.h>

#define EPS 1e-6f

typedef __attribute__((ext_vector_type(8))) __bf16 bf16x8;
typedef __attribute__((ext_vector_type(4))) float f32x4;

// ---------------------------------------------------------------------------
// Fully fused yat-similarity kernel — 256x256 tile, 1024 threads, reg-trimmed.
// 16 waves (4x4 grid, 64x64 per wave) => 4 waves/SIMD (needs <=128 regs/wave:
// acc 64 in AGPR + <=64 VGPR-side). vs r9: removed sched_barrier(0) from the
// phase barrier (was pinning live ranges across barriers -> marginal spill)
// and setprio (negative on lockstep GEMM, m190). Everything else identical.
// f32 inputs reg-staged (2x 8-reg ping-pong chunks, issue->write = 1 phase),
// bf16 RTNE cvt + row sum-of-squares at write time.
// out = dots^2 / (xsq + psq - 2*dots + eps)
// ---------------------------------------------------------------------------
__global__ __launch_bounds__(1024, 4) void yat_fused(
    const float* __restrict__ X, const float* __restrict__ Pr,
    float* __restrict__ out, int M, int N, int K) {

    __shared__ __align__(128) char sm[131072];   // 2 slots x (A 32KB + B 32KB)
    __shared__ __align__(16) float sqx[256];
    __shared__ __align__(16) float sqp[256];
    const char* smc = (const char*)sm;

    const int t = threadIdx.x;
    const int lane = t & 63;
    const int wid = t >> 6;        // 0..15
    const int wr = wid >> 2;       // 0..3  (64-row band)
    const int wc = wid & 3;        // 0..3  (64-col band)

    // T1: bijective XCD swizzle (total % 8 == 0 guaranteed by launch guard)
    const int nbx = N >> 8;
    const int nby = M >> 8;
    const int total = nbx * nby;
    int bid = blockIdx.x;
    bid = (bid & 7) * (total >> 3) + (bid >> 3);
    const int by = bid / nbx;
    const int bx = bid - by * nbx;
    const int brow = by << 8;
    const int bcol = bx << 8;

    const int NKT = K >> 6;         // K-tiles (16)

    f32x4 acc[4][4];
#pragma unroll
    for (int i = 0; i < 4; ++i)
#pragma unroll
        for (int j = 0; j < 4; ++j) acc[i][j] = (f32x4){0.f, 0.f, 0.f, 0.f};

    const int arow = lane & 15;           // fragment row/col within 16
    const int kq16 = (lane >> 4) * 16;    // byte offset of k-slot within 32-k half

    // ---- staging geometry ----
    // Chunk s in {0,1}: thread owns row rl = s*128 + wid*8 + (lane>>3) of the
    // 256-row panel, logical col16 lcq = (lane&7)^(lane>>3) (pre-swizzled so
    // the LDS image lands at physical col16 = lane&7, i.e. byte lane*16).
    const int rsub = lane >> 3;
    const int lcq = (lane & 7) ^ rsub;
    const long baseA = (long)(brow + wid * 8 + rsub) * K + lcq * 8;
    const long baseB = (long)(bcol + wid * 8 + rsub) * K + lcq * 8;
    const long sH = (long)128 * K;  // uniform (SGPR)
    const int dlane = wid * 1024 + lane * 16;

    f32x4 c0[2], c1[2];             // ping-pong chunk buffers (8 regs each)
    float qA[2] = {0.f, 0.f};       // per-thread sum-of-squares
    float qB[2] = {0.f, 0.f};

    // issue chunk: 2 f32x4 = 8 k-elems of row-chunk s of one matrix, tile kt
#define ISSUE(buf, G, BASE, s, kt) do {                                        \
    const float* g0_ = (G) + BASE + (s) * sH + (long)(kt) * 64;                \
    buf[0] = *(const f32x4*)(g0_);                                             \
    buf[1] = *(const f32x4*)(g0_ + 4);                                         \
} while (0)

    // cvt + sumsq + ds_write chunk into slot (boff = 0 for A, 32768 for B)
#define WRITE(buf, Q, s, slot, boff) do {                                      \
    f32x4 u_ = buf[0], v_ = buf[1];                                            \
    Q[s] += u_[0]*u_[0] + u_[1]*u_[1] + u_[2]*u_[2] + u_[3]*u_[3]              \
          + v_[0]*v_[0] + v_[1]*v_[1] + v_[2]*v_[2] + v_[3]*v_[3];             \
    bf16x8 pk_;                                                                \
    _Pragma("unroll")                                                          \
    for (int i_ = 0; i_ < 4; ++i_) {                                           \
        pk_[i_]     = (__bf16)u_[i_];                                          \
        pk_[4 + i_] = (__bf16)v_[i_];                                          \
    }                                                                          \
    *(bf16x8*)((char*)sm + (slot) * 65536 + (boff) + (s) * 16384 + dlane) = pk_;\
} while (0)

    // read A/B fragments for one 32-k slice kk of the 64-k tile
#define READ_A(slot, kk) do {                                                  \
    _Pragma("unroll")                                                          \
    for (int mi_ = 0; mi_ < 4; ++mi_) {                                        \
        int r_ = wr * 64 + mi_ * 16 + arow;                                    \
        const char* p_ = smc + (slot) * 65536 + r_ * 128;                      \
        int s_ = (r_ & 7) << 4;                                                \
        af[mi_] = *(const bf16x8*)(p_ + (((kk) * 64 + kq16) ^ s_));            \
    }                                                                          \
} while (0)

#define READ_B(slot, kk) do {                                                  \
    _Pragma("unroll")                                                          \
    for (int ni_ = 0; ni_ < 4; ++ni_) {                                        \
        int r_ = wc * 64 + ni_ * 16 + arow;                                    \
        const char* p_ = smc + (slot) * 65536 + 32768 + r_ * 128;              \
        int s_ = (r_ & 7) << 4;                                                \
        bf[ni_] = *(const bf16x8*)(p_ + (((kk) * 64 + kq16) ^ s_));            \
    }                                                                          \
} while (0)

#define MFMA_S() do {                                                          \
    _Pragma("unroll")                                                          \
    for (int mi_ = 0; mi_ < 4; ++mi_)                                          \
        _Pragma("unroll")                                                      \
        for (int ni_ = 0; ni_ < 4; ++ni_)                                      \
            acc[mi_][ni_] = __builtin_amdgcn_mfma_f32_16x16x32_bf16(           \
                af[mi_], bf[ni_], acc[mi_][ni_], 0, 0, 0);                     \
} while (0)

#define PBAR() do {                                                            \
    __builtin_amdgcn_s_barrier();                                              \
    asm volatile("" ::: "memory");                                             \
} while (0)
#define LGKMDRAIN() asm volatile("s_waitcnt lgkmcnt(0)" ::: "memory")

    bf16x8 af[4];                 // A frags, one 32-k slice
    bf16x8 bf[4];                 // B frags, one 32-k slice

    // prologue: stage tile 0 via chunk ping-pong; leave c0/c1 = A(kt=1).
    ISSUE(c0, X, baseA, 0, 0);  ISSUE(c1, X, baseA, 1, 0);
    WRITE(c0, qA, 0, 0, 0);     WRITE(c1, qA, 1, 0, 0);
    ISSUE(c0, Pr, baseB, 0, 0); ISSUE(c1, Pr, baseB, 1, 0);
    WRITE(c0, qB, 0, 0, 32768); WRITE(c1, qB, 1, 0, 32768);
    if (NKT > 1) { ISSUE(c0, X, baseA, 0, 1); ISSUE(c1, X, baseA, 1, 1); }
    LGKMDRAIN();
    PBAR();

    for (int kt = 0; kt < NKT; ++kt) {
        const int slot = kt & 1;
        const int nslot = slot ^ 1;
        const bool more = (kt + 1) < NKT;
        const bool more2 = (kt + 2) < NKT;

        // ph1: write A(kt+1) -> nslot, issue B(kt+1); compute k-slice 0
        if (more) {
            WRITE(c0, qA, 0, nslot, 0);  ISSUE(c0, Pr, baseB, 0, kt + 1);
            WRITE(c1, qA, 1, nslot, 0);  ISSUE(c1, Pr, baseB, 1, kt + 1);
        }
        READ_A(slot, 0); READ_B(slot, 0);
        MFMA_S(); PBAR();
        // ph2: write B(kt+1) -> nslot, prime A(kt+2); compute k-slice 1
        if (more) {
            WRITE(c0, qB, 0, nslot, 32768);
            WRITE(c1, qB, 1, nslot, 32768);
        }
        if (more2) { ISSUE(c0, X, baseA, 0, kt + 2); ISSUE(c1, X, baseA, 1, kt + 2); }
        READ_A(slot, 1); READ_B(slot, 1);
        MFMA_S();
        LGKMDRAIN();
        PBAR();
    }

#undef ISSUE
#undef WRITE
#undef READ_A
#undef READ_B
#undef MFMA_S
#undef PBAR
#undef LGKMDRAIN

    // ---- reduce per-thread sum-of-squares into sqx/sqp ----
    // Row (s*128 + wid*8 + rsub) is covered by the 8 lanes sharing rsub:
    // 3-step shfl_xor over lane&7.
#pragma unroll
    for (int s = 0; s < 2; ++s) {
        float a = qA[s], b = qB[s];
#pragma unroll
        for (int m = 1; m <= 4; m <<= 1) {
            a += __shfl_xor(a, m);
            b += __shfl_xor(b, m);
        }
        if ((lane & 7) == 0) {
            int r = s * 128 + wid * 8 + rsub;
            sqx[r] = a;
            sqp[r] = b;
        }
    }

    // epilogue: score = d^2 / (xsq + psq - 2d + eps), staged through LDS
    // (128 rows x 256 cols f32 = 128KB = sm) for full-line f32x4 stores.
    // Two passes of 128 rows (wr>>1 half each). Swizzle: logical (row,col)
    // at physical col ^ (((row>>2)&1)<<4); reader loads physical
    // (c0l)^swz (logical cols [c0l,+3]) and stores to bcol + c0l.
    float* smf = (float*)sm;
#pragma unroll
    for (int pass = 0; pass < 2; ++pass) {
        __syncthreads();
        if ((wr >> 1) == pass) {
            const int wrl = wr & 1;
#pragma unroll
            for (int ni = 0; ni < 4; ++ni) {
                int lcc = wc * 64 + ni * 16 + arow;
                float ps = sqp[lcc];
#pragma unroll
                for (int mi = 0; mi < 4; ++mi) {
                    f32x4 c = acc[mi][ni];
                    int lr0 = wrl * 64 + mi * 16 + (lane >> 4) * 4;  // mult of 4
                    f32x4 xs4 = *(const f32x4*)(&sqx[pass * 128 + lr0]);
                    int lcs = lcc ^ (((lr0 >> 2) & 1) << 4);
#pragma unroll
                    for (int j = 0; j < 4; ++j) {
                        float dv = c[j];
                        float denom = xs4[j] + ps - 2.0f * dv + EPS;
                        smf[(lr0 + j) * 256 + lcs] = dv * dv / denom;
                    }
                }
            }
        }
        __syncthreads();
#pragma unroll
        for (int it = 0; it < 8; ++it) {
            int r = it * 16 + (t >> 6);
            int swz = ((r >> 2) & 1) << 4;
            int c0l = (t & 63) * 4;                         // logical col
            f32x4 v = *(const f32x4*)(smf + r * 256 + (c0l ^ swz));
            *(f32x4*)(out + (size_t)(brow + pass * 128 + r) * N + bcol + c0l) = v;
        }
    }
}

__global__ void yat_fallback(const float* __restrict__ x, const float* __restrict__ p,
                             float* __restrict__ out, int B, int P, int D) {
    __shared__ float xs[1024];
    int b = blockIdx.x;
    int pc = blockIdx.y * 256 + threadIdx.x;
    for (int i = threadIdx.x; i < D; i += 256) xs[i] = x[(size_t)b * D + i];
    __syncthreads();
    if (pc >= P) return;
    float dot = 0.f, psq = 0.f, xsq = 0.f;
    for (int k = 0; k < D; ++k) {
        float pv = p[(size_t)pc * D + k];
        float xv = xs[k];
        dot += xv * pv;
        psq += pv * pv;
        xsq += xv * xv;
    }
    float denom = xsq + psq - 2.f * dot + EPS;
    out[(size_t)b * P + pc] = dot * dot / denom;
}

extern "C" void kernel_launch(void* const* d_in, const int* in_sizes, int n_in,
                              void* d_out, int out_size, void* d_ws, size_t ws_size,
                              hipStream_t stream) {
    const float* x = (const float*)d_in[0];
    const float* p = (const float*)d_in[1];
    float* out = (float*)d_out;

    const int D = 1024;
    const int B = in_sizes[0] / D;
    const int P = in_sizes[1] / D;

    int nblocks = (B / 256) * (P / 256);
    if ((B % 256) || (P % 256) || (D % 64) || (nblocks % 8)) {
        yat_fallback<<<dim3(B, (P + 255) / 256), 256, 0, stream>>>(x, p, out, B, P, D);
        return;
    }

    yat_fused<<<dim3(nblocks), 1024, 0, stream>>>(x, p, out, B, P, D);
}